// Round 4
// baseline (349.558 us; speedup 1.0000x reference)
//
#include <hip/hip_runtime.h>

// Resample OLD_SR=4 -> NEW_SR=5, polyphase windowed-sinc, K=56 taps, pad=26 (edge/replicate).
// out[b, 5n+i] = sum_k x[b, clamp(4n + k - 26, 0, T-1)] * kernel[i, k],  n in [0, 262144)
//
// R3 structure: block stages input span to LDS (+1/16 pad); each thread PREFETCHES its
// 68 taps LDS->VGPR (single lgkmcnt region), then a pure-FMA stream whose only memory
// ops are batched SMEM coefficient loads (i-outer/k-inner -> consecutive s_load_dwordx8).
// Keeping DS and SMEM phases disjoint avoids lgkmcnt(0) drains of the LDS pipe.

#define OLD_SR  4
#define NEW_SR  5
#define KW      56
#define T_LEN   1048576
#define N_PER_ROW 262144
#define OUT_PER_ROW (N_PER_ROW * NEW_SR)   // 1310720
#define R       4
#define TPB     256
#define NB      (TPB * R)                  // 1024 positions n per block
#define SPAN    (NB * OLD_SR)              // 4096 net input floats per block
#define STAGE_N 4152                       // staged span incl. halo, 16B-aligned origin
#define STAGE_V4 (STAGE_N / 4)             // 1038
#define PHYS(i) ((i) + ((i) >> 4))         // +1 pad per 16 floats
#define LDS_SZ  (PHYS(STAGE_N - 1) + 1)    // 4411 floats
#define NTAP    (4 * (R - 1) + KW)         // 68 unique taps per thread

__global__ __launch_bounds__(TPB) void resample_poly_kernel(
    const float* __restrict__ x,
    const float* __restrict__ krn,     // [NEW_SR][KW] row-major
    float* __restrict__ out)
{
    __shared__ float lds[LDS_SZ];
    const int tid = threadIdx.x;
    const int bx  = blockIdx.x;
    const int b   = blockIdx.y;
    const long long row_in  = (long long)b * T_LEN;
    const long long row_out = (long long)b * OUT_PER_ROW;
    const int sbase = bx * SPAN - 28;      // 16B-aligned staging origin

    // ---- stage global -> LDS (padded) ----
    if (sbase >= 0 && sbase + STAGE_N <= T_LEN) {
        const float4* xv = reinterpret_cast<const float4*>(x + row_in + sbase);
        for (int q = tid; q < STAGE_V4; q += TPB) {
            float4 v = xv[q];
            int p = PHYS(4 * q);           // 4q..4q+3 stay within one 16-group
            lds[p + 0] = v.x;
            lds[p + 1] = v.y;
            lds[p + 2] = v.z;
            lds[p + 3] = v.w;
        }
    } else {
        for (int s = tid; s < STAGE_N; s += TPB) {
            int g = sbase + s;
            g = g < 0 ? 0 : (g > T_LEN - 1 ? T_LEN - 1 : g);
            lds[PHYS(s)] = x[row_in + g];
        }
    }
    __syncthreads();

    // ---- prefetch all 68 taps to VGPRs: lane base stride 17 -> 2/bank (free) ----
    float w[NTAP];
    const int pbase = 17 * tid;            // PHYS(16*tid)
    #pragma unroll
    for (int j = 0; j < NTAP; ++j)
        w[j] = lds[pbase + (2 + j) + ((2 + j) >> 4)];   // compile-time offsets

    // Keep all ds_reads issued/consumed before the SMEM-interleaved FMA region.
    __builtin_amdgcn_sched_barrier(0);

    // ---- pure FMA stream; coefficients via batched scalar loads ----
    float acc[R * NEW_SR];
    #pragma unroll
    for (int m = 0; m < R * NEW_SR; ++m) acc[m] = 0.0f;

    #pragma unroll
    for (int i = 0; i < NEW_SR; ++i) {
        #pragma unroll
        for (int k = 0; k < KW; ++k) {
            const float c = krn[i * KW + k];   // consecutive addrs -> s_load_dwordx8 batches
            #pragma unroll
            for (int r = 0; r < R; ++r)
                acc[r * NEW_SR + i] = fmaf(w[4 * r + k], c, acc[r * NEW_SR + i]);
        }
    }

    // ---- store: 20 consecutive floats, 16B aligned ----
    float4* ov = reinterpret_cast<float4*>(out + row_out +
                                           (long long)(bx * NB + 4 * tid) * NEW_SR);
    #pragma unroll
    for (int q = 0; q < (R * NEW_SR) / 4; ++q) {
        float4 v;
        v.x = acc[4 * q + 0];
        v.y = acc[4 * q + 1];
        v.z = acc[4 * q + 2];
        v.w = acc[4 * q + 3];
        ov[q] = v;
    }
}

extern "C" void kernel_launch(void* const* d_in, const int* in_sizes, int n_in,
                              void* d_out, int out_size, void* d_ws, size_t ws_size,
                              hipStream_t stream) {
    const float* x   = (const float*)d_in[0];
    const float* krn = (const float*)d_in[1];
    float* out = (float*)d_out;

    const int B = in_sizes[0] / T_LEN;     // 32
    dim3 grid(N_PER_ROW / NB, B);          // (256, 32)
    resample_poly_kernel<<<grid, TPB, 0, stream>>>(x, krn, out);
}